// Round 9
// baseline (359.893 us; speedup 1.0000x reference)
//
#include <hip/hip_runtime.h>

// WaveFDTD2D, persistent fenceless-sync kernel, 8 waves x 8 rows (r21).
// r20b (262us dispatch): protocol trims neutral -> fixed cost is NOT poll/
// prefill/flush. Model: ~1200cy/substep wall, ~270cy VALU issue. Dominant
// term = per-substep serial chain (ds_write -> barrier -> ds_read ~120cy ->
// dep chain), 16 waves lockstep, 1 block/CU, only 2 of 4 rows per wave
// independent of the LDS read.
// r21: SAME tile (32x32), ext (64x64), protocol, init, cone, LDS layout --
// but 8 waves x 8 rows/wave (512 thr). Per substep each wave has 6
// REGISTER-ONLY rows (~120cy issue) to hide the 2 halo ds_reads, and the
// barrier convoy is 8 waves not 16. Same total VALU, same redundancy.
// Interior rows computed first so the compiler sinks the lgkmcnt wait.
// Everything else byte-identical to r20b (validated): agent-scope coherent-
// point field exchange, all-wave 8-neighbor polling, no prefill (s=0 x-halo
// from global, guard rows in workspace), receiver flush after publish.

#define NXd 512
#define NZd 512
#define NSTEPSd 512
#define NRECd 128
#define DT2f 1.0e-6f
#define INVf 1.0e-2f
#define TBk 16
#define TIk 32
#define EXTk 64
#define NTILEk 16
#define PADk 16
#define PWk 544              // NXd + 2*PADk = 16*34
#define LROWS 66             // 1 dummy + 64 ext rows + 1 dummy
#define NROUNDS (NSTEPSd / TBk)
#define RPW 8                // ext rows per wave
#define NTHR 512             // 8 waves

__device__ __forceinline__ float dpp_shr1(float x) {  // lane i <- lane i-1
    int v = __builtin_amdgcn_update_dpp(0, __builtin_bit_cast(int, x),
                                        0x138, 0xF, 0xF, false);  // WAVE_SHR:1
    return __builtin_bit_cast(float, v);
}
__device__ __forceinline__ float dpp_shl1(float x) {  // lane i <- lane i+1
    int v = __builtin_amdgcn_update_dpp(0, __builtin_bit_cast(int, x),
                                        0x130, 0xF, 0xF, false);  // WAVE_SHL:1
    return __builtin_bit_cast(float, v);
}

// Coherent-point (agent-scope) field accesses: bypass L1/L2, hit L3.
__device__ __forceinline__ float2 ldg_f2(const float2* p) {
    unsigned long long v = __hip_atomic_load(
        (const unsigned long long*)p, __ATOMIC_RELAXED, __HIP_MEMORY_SCOPE_AGENT);
    return __builtin_bit_cast(float2, v);
}
__device__ __forceinline__ float ldg_f1(const float* p) {
    unsigned v = __hip_atomic_load(
        (const unsigned*)p, __ATOMIC_RELAXED, __HIP_MEMORY_SCOPE_AGENT);
    return __builtin_bit_cast(float, v);
}
__device__ __forceinline__ void stg_f2(float2* p, float2 x) {
    __hip_atomic_store((unsigned long long*)p,
                       __builtin_bit_cast(unsigned long long, x),
                       __ATOMIC_RELAXED, __HIP_MEMORY_SCOPE_AGENT);
}

__global__ __launch_bounds__(NTHR) void fdtd_persist(
    const float* __restrict__ vel, const float* __restrict__ source,
    const int* __restrict__ src_x, const int* __restrict__ src_z,
    const int* __restrict__ rec_x, const int* __restrict__ rec_z,
    float2* __restrict__ PA, float2* __restrict__ PB,
    float* __restrict__ out, unsigned* __restrict__ done)
{
    __shared__ float sb[2][LROWS * EXTk];

    const int tid = threadIdx.x;
    const int w   = tid >> 6;       // 8 waves, wave w owns ext rows 8w..8w+7
    const int ez  = tid & 63;       // lane -> ext z coord
    const int bx = blockIdx.x, by = blockIdx.y;
    const int gx0 = by * TIk;
    const int gz0 = bx * TIk;
    const int ox = gx0 - TBk, oz = gz0 - TBk;
    const int myid = (by * NTILEk + bx) * 32;   // 128B-strided counter slot

    // ---- Block-local init: zero own 34x34 padded patch of PA and PB ----
    for (int i = tid; i < 34 * 34; i += NTHR) {
        const int p = (by * 34 + i / 34) * PWk + (bx * 34 + i % 34);
        stg_f2(&PA[p], make_float2(0.f, 0.f));
        stg_f2(&PB[p], make_float2(0.f, 0.f));
    }

    // O(1) receiver ownership; owning block zeros its receivers' out rows.
    bool rOwn = false; int rIdx = 0;
    if (tid < NRECd) {
        const int rx = rec_x[tid], rz = rec_z[tid];
        rOwn = (rx >= gx0 && rx < gx0 + TIk && rz >= gz0 && rz < gz0 + TIk);
        rIdx = (rx - ox + 1) * EXTk + (rz - oz);    // buffer row = ext row + 1
        if (rOwn) {
            float4* o4 = (float4*)&out[tid * NSTEPSd];
            #pragma unroll
            for (int j = 0; j < NSTEPSd / 4; ++j) o4[j] = make_float4(0.f, 0.f, 0.f, 0.f);
        }
    }

    // V2 in 8 registers per thread for the whole run: v^2*dt^2/(dx*dz),
    // 0 in the apron (zero BC) -- never touches global memory.
    float rV2i[RPW];
    {
        const int fz = oz + ez;
        #pragma unroll
        for (int i = 0; i < RPW; ++i) {
            const int fx = ox + RPW * w + i;
            float v2 = 0.f;
            if (fx >= 0 && fx < NXd && fz >= 0 && fz < NZd) {
                float v = vel[fx * NZd + fz];
                v2 = v * v * (DT2f * INVf);
            }
            rV2i[i] = v2;
        }
    }

    // Dummy LDS rows (0 and 65) zero in BOTH buffers; never rewritten.
    if (w == 0) {
        sb[0][ez] = 0.f;
        sb[0][(LROWS - 1) * EXTk + ez] = 0.f;
        sb[1][ez] = 0.f;
        sb[1][(LROWS - 1) * EXTk + ez] = 0.f;
    }

    // Source ownership (owner = lane ezs of wave exs>>3, register exs&7).
    const int sx = *src_x, sz = *src_z;
    const int exs = sx - ox, ezs = sz - oz;
    const bool srcHere = (exs >= 0 && exs < EXTk && ezs >= 0 && ezs < EXTk) &&
                         (tid == (((exs >> 3) << 6) | ezs));

    // Exact L1 cone: active at round k iff dman <= 16k+17.
    const int dxm = max(0, max(ox - sx, sx - (ox + EXTk - 1)));
    const int dzm = max(0, max(oz - sz, sz - (oz + EXTk - 1)));
    const int dman = dxm + dzm;
    const int kAct = dman <= (TBk + 1) ? 0 : (dman - (TBk + 1) + TBk - 1) / TBk;

    // Every wave polls: lanes 0-7 of each wave watch the 8 neighbors
    // (clamped; clamp->self benign: own counter == k+1 entering round k).
    const int lane = tid & 63;
    int nb = myid;
    if (lane < 8) {
        const int d = (lane < 4) ? lane : lane + 1;       // skip center
        const int ny = min(NTILEk - 1, max(0, by + d / 3 - 1));
        const int nx = min(NTILEk - 1, max(0, bx + d % 3 - 1));
        nb = (ny * NTILEk + nx) * 32;
    }

    const int pbase = (gx0 + RPW * w) * PWk + gz0 + ez;  // padded global index
    const int fbase = RPW * w * EXTk + ez;  // buffer row 8w (ext row 8w-1)

    // Publish init + entire cone-skipped prefix in one release store
    // (barrier drains every wave's vmcnt; agent stores visible at L3).
    __syncthreads();
    if (tid == 0)
        __hip_atomic_store(&done[myid], (unsigned)(kAct + 1),
                           __ATOMIC_RELAXED, __HIP_MEMORY_SCOPE_AGENT);

    // ---- Rounds kAct..31; monotone cone => always active once started ----
    for (int k = kAct; k < NROUNDS; ++k) {
        const int t0 = TBk * k;

        // Per-wave wait: 8 neighbors finished round k-1 (reads AND writes).
        if (lane < 8) {
            const unsigned tgt = (unsigned)(k + 1);
            for (;;) {
                unsigned seen = __hip_atomic_load(&done[nb], __ATOMIC_RELAXED,
                                                  __HIP_MEMORY_SCOPE_AGENT);
                if (seen >= tgt) break;
                if (seen + 1 < tgt) __builtin_amdgcn_s_sleep(16);
                else                __builtin_amdgcn_s_sleep(1);
            }
        }

        float2* __restrict__ Pin  = (k & 1) ? PB : PA;
        float2* __restrict__ Pout = (k & 1) ? PA : PB;

        // Unconditional padded agent loads (apron zeros / tolerated rim).
        float2 co[RPW];
        #pragma unroll
        for (int i = 0; i < RPW; ++i) co[i] = ldg_f2(&Pin[pbase + i * PWk]);
        // Substep-0 x-halo direct from global: cur of ext rows 8w-1, 8w+8.
        // Edge blocks read guard rows (allocated; values tolerated).
        const float huG = ldg_f1((const float*)&Pin[pbase - PWk]);
        const float hdG = ldg_f1((const float*)&Pin[pbase + RPW * PWk]);

        float rCur[RPW], rOld[RPW];
        #pragma unroll
        for (int i = 0; i < RPW; ++i) { rCur[i] = co[i].x; rOld[i] = co[i].y; }

        float sv[TBk];
        if (srcHere) {
            #pragma unroll
            for (int s = 0; s < TBk; ++s) sv[s] = source[t0 + s] * DT2f;
        }

        // ---- 16 sub-steps, fully unrolled; s=0 uses global halo ----
        float rv[TBk];
        #pragma unroll
        for (int s = 0; s < TBk; ++s) {
            const float* cur = sb[s & 1];
            float* nxt = sb[(s & 1) ^ 1];
            // x-halo: s=0 from global regs; s>=1 wave-uniform ds_read2st64
            // (ext rows 8w-1, 8w+8; edge waves hit zero dummies).
            const float up0 = (s == 0) ? huG : cur[fbase];
            const float dn7 = (s == 0) ? hdG : cur[fbase + (RPW + 1) * EXTk];
            float nv[RPW];
            // Interior rows 1..6 first: register-only, hide the ds_read.
            #pragma unroll
            for (int i = 1; i < RPW - 1; ++i) {
                const float c = rCur[i];
                const float sum = (rCur[i - 1] + rCur[i + 1]) +
                                  (dpp_shr1(c) + dpp_shl1(c));
                const float t4 = __builtin_fmaf(-4.0f, c, sum);
                const float pm = __builtin_fmaf(2.0f, c, -rOld[i]);
                nv[i] = __builtin_fmaf(rV2i[i], t4, pm);
            }
            // Edge rows 0 and 7: need the LDS halo.
            {
                const float c0 = rCur[0];
                const float s0 = (up0 + rCur[1]) + (dpp_shr1(c0) + dpp_shl1(c0));
                nv[0] = __builtin_fmaf(rV2i[0], __builtin_fmaf(-4.0f, c0, s0),
                                       __builtin_fmaf(2.0f, c0, -rOld[0]));
                const float c7 = rCur[RPW - 1];
                const float s7 = (rCur[RPW - 2] + dn7) + (dpp_shr1(c7) + dpp_shl1(c7));
                nv[RPW - 1] = __builtin_fmaf(rV2i[RPW - 1],
                                             __builtin_fmaf(-4.0f, c7, s7),
                                             __builtin_fmaf(2.0f, c7, -rOld[RPW - 1]));
            }
            #pragma unroll
            for (int i = 0; i < RPW; ++i) {
                rOld[i] = rCur[i];
                rCur[i] = nv[i];
                nxt[fbase + (1 + i) * EXTk] = nv[i];    // buffer row 8w+1+i
            }
            // Source injection (post-stencil, pre-recording).
            if (srcHere) {
                #pragma unroll
                for (int i = 0; i < RPW; ++i) {
                    if (i == (exs & 7)) {
                        rCur[i] += sv[s];
                        nxt[(exs + 1) * EXTk + ezs] = rCur[i];
                    }
                }
            }
            __syncthreads();
            // Receiver sample of field@t0+s (post-injection). Next substep
            // writes the OTHER buffer -> race-free with one barrier.
            if (rOwn) rv[s] = nxt[rIdx];
        }

        // Store interior (ext rows 16..47 = waves 2..5, ez 16..47): agent
        // stores, visible to neighbors' agent loads without any fence.
        if (w >= 2 && w < 6 && ez >= TBk && ez < EXTk - TBk) {
            #pragma unroll
            for (int i = 0; i < RPW; ++i)
                stg_f2(&Pout[pbase + i * PWk], make_float2(rCur[i], rOld[i]));
        }

        // Pre-publish barrier: every wave's vmcnt (agent-store acks) drained
        // before tid 0 issues the counter store. Also the block-internal
        // round serializer for the all-wave-poll scheme.
        __syncthreads();
        if (tid == 0)
            __hip_atomic_store(&done[myid], (unsigned)(k + 2),
                               __ATOMIC_RELAXED, __HIP_MEMORY_SCOPE_AGENT);

        // Receiver flush AFTER publish (block-private, off critical path).
        if (rOwn) {
            #pragma unroll
            for (int s = 0; s < TBk; ++s)
                out[tid * NSTEPSd + t0 + s] = rv[s];
        }
    }
}

extern "C" void kernel_launch(void* const* d_in, const int* in_sizes, int n_in,
                              void* d_out, int out_size, void* d_ws, size_t ws_size,
                              hipStream_t stream) {
    const float* vel    = (const float*)d_in[0];
    const float* source = (const float*)d_in[1];
    const int*   src_x  = (const int*)d_in[2];
    const int*   src_z  = (const int*)d_in[3];
    const int*   rec_x  = (const int*)d_in[4];
    const int*   rec_z  = (const int*)d_in[5];
    float* out = (float*)d_out;

    const size_t FP = (size_t)PWk * PWk;
    // Guard rows: [guard PWk][PA FP][PB FP][guard PWk][DONE]. PA's top OOB
    // (row -1) lands in the leading guard; PB's bottom OOB (row PWk) lands
    // in the trailing guard; PA-bottom/PB-top OOB land inside PB/PA.
    float2* base = (float2*)d_ws;
    float2* PA = base + PWk;
    float2* PB = PA + FP;
    unsigned* DONE = (unsigned*)(PB + FP + PWk);   // 256 counters, 128B stride

    hipMemsetAsync(DONE, 0, (size_t)NTILEk * NTILEk * 32 * sizeof(unsigned), stream);

    void* args[] = {(void*)&vel, (void*)&source, (void*)&src_x, (void*)&src_z,
                    (void*)&rec_x, (void*)&rec_z, (void*)&PA, (void*)&PB,
                    (void*)&out, (void*)&DONE};
    hipLaunchCooperativeKernel((void*)fdtd_persist, dim3(NTILEk, NTILEk),
                               dim3(NTHR), args, 0, stream);
}